// Round 2
// baseline (494.004 us; speedup 1.0000x reference)
//
#include <hip/hip_runtime.h>
#include <stdint.h>

#define B_   64
#define N_   4096
#define H_   128
#define S_   7
#define D_   32
#define SCALE_ 0.17677669529663687f   // 32^-0.5
#define EPS_   1e-8f
#define LNEPS_ 1e-5f

// ---------------------------------------------------------------- LN(inputs) -> k,v projections (f32)
__global__ __launch_bounds__(256) void ln_kv(const float* __restrict__ x,
                                             const float* __restrict__ Wk, const float* __restrict__ Wv,
                                             const float* __restrict__ g,  const float* __restrict__ bta,
                                             float* __restrict__ kb, float* __restrict__ vb){
  int row = blockIdx.x * 256 + threadIdx.x;          // 262144 rows
  const float* xr = x + (size_t)row * H_;
  float xn[128];
  #pragma unroll
  for (int p = 0; p < 32; ++p){
    float4 u = *reinterpret_cast<const float4*>(xr + p * 4);
    xn[p*4+0]=u.x; xn[p*4+1]=u.y; xn[p*4+2]=u.z; xn[p*4+3]=u.w;
  }
  float s = 0.f, s2 = 0.f;
  #pragma unroll
  for (int d = 0; d < 128; ++d){ s += xn[d]; s2 += xn[d] * xn[d]; }
  float mean = s * (1.f / 128.f);
  float var  = s2 * (1.f / 128.f) - mean * mean;
  float rstd = rsqrtf(var + LNEPS_);
  #pragma unroll
  for (int d = 0; d < 128; ++d) xn[d] = (xn[d] - mean) * rstd * g[d] + bta[d];

  float* ko = kb + (size_t)row * 32;
  float* vo = vb + (size_t)row * 32;
  for (int c = 0; c < 32; c += 2){                  // rolled: W reads are wave-uniform -> s_load
    const float* wk0 = Wk + (c    ) * 128;
    const float* wk1 = Wk + (c + 1) * 128;
    const float* wv0 = Wv + (c    ) * 128;
    const float* wv1 = Wv + (c + 1) * 128;
    float ka0 = 0.f, ka1 = 0.f, va0 = 0.f, va1 = 0.f;
    #pragma unroll
    for (int d = 0; d < 128; ++d){
      float xv = xn[d];
      ka0 += xv * wk0[d]; ka1 += xv * wk1[d];
      va0 += xv * wv0[d]; va1 += xv * wv1[d];
    }
    float2 kp = make_float2(ka0, ka1);
    float2 vp = make_float2(va0, va1);
    *reinterpret_cast<float2*>(ko + c) = kp;
    *reinterpret_cast<float2*>(vo + c) = vp;
  }
}

// ---------------------------------------------------------------- per-iteration attention accumulation
// grid: (8 chunks, 64 batches), 256 threads. Each block: 512 j's in 2 tiles of 256.
__global__ __launch_bounds__(256) void attn_acc(const float* __restrict__ kb, const float* __restrict__ vb,
                                                const float* __restrict__ qbuf,
                                                float* __restrict__ updbuf, float* __restrict__ rowsumbuf,
                                                float* __restrict__ aub, int lastIter){
  __shared__ float au[S_ * 257];       // [7][257] padded
  __shared__ float vtile[256 * 32];    // [256][32] f32, XOR-swizzled float4 blocks
  int b = blockIdx.y, chunk = blockIdx.x, t = threadIdx.x;

  int rem = t % 56, prt = t / 56;      // valid for t<224
  int pi = rem >> 3, pc4 = rem & 7;

  float rs[7];
  #pragma unroll
  for (int i = 0; i < 7; ++i) rs[i] = 0.f;
  float ux = 0.f, uy = 0.f, uz = 0.f, uw = 0.f;

  const float* qb = qbuf + b * (S_ * D_);           // wave-uniform -> s_load

  for (int tile = 0; tile < 2; ++tile){
    int j = chunk * 512 + tile * 256 + t;
    const float* kr = kb + ((size_t)b * N_ + j) * 32;
    float kf[32];
    #pragma unroll
    for (int p = 0; p < 8; ++p){
      float4 u = *reinterpret_cast<const float4*>(kr + p * 4);
      kf[p*4+0]=u.x; kf[p*4+1]=u.y; kf[p*4+2]=u.z; kf[p*4+3]=u.w;
    }

    float dv[7];
    #pragma unroll
    for (int i = 0; i < 7; ++i){
      const float* qr = qb + i * 32;
      float a = 0.f;
      #pragma unroll
      for (int c = 0; c < 32; ++c) a += qr[c] * kf[c];
      dv[i] = a * SCALE_;
    }
    float mx = dv[0];
    #pragma unroll
    for (int i = 1; i < 7; ++i) mx = fmaxf(mx, dv[i]);
    float p[7]; float sum = 0.f;
    #pragma unroll
    for (int i = 0; i < 7; ++i){ p[i] = __expf(dv[i] - mx); sum += p[i]; }
    float inv = 1.f / sum;
    #pragma unroll
    for (int i = 0; i < 7; ++i){
      p[i] = p[i] * inv + EPS_;
      rs[i] += p[i];
      au[i * 257 + t] = p[i];
    }
    if (lastIter){
      #pragma unroll
      for (int i = 0; i < 7; ++i) aub[(size_t)(b * S_ + i) * N_ + j] = p[i];
    }
    // stage v tile (f32, XOR-swizzled 16B blocks: logical block q4 stored at q4^(t&7))
    const float* vr = vb + ((size_t)b * N_ + j) * 32;
    #pragma unroll
    for (int q4 = 0; q4 < 8; ++q4){
      int blk = q4 ^ (t & 7);
      float4 vv = *reinterpret_cast<const float4*>(vr + q4 * 4);
      *reinterpret_cast<float4*>(&vtile[t * 32 + blk * 4]) = vv;
    }
    __syncthreads();

    if (t < 224){
      const float* aur = au + pi * 257 + prt * 64;
      #pragma unroll 4
      for (int jj0 = 0; jj0 < 64; ++jj0){
        int jj = prt * 64 + jj0;
        float a = aur[jj0];
        int blk = pc4 ^ (jj & 7);
        float4 vv = *reinterpret_cast<const float4*>(&vtile[jj * 32 + blk * 4]);
        ux += a * vv.x; uy += a * vv.y; uz += a * vv.z; uw += a * vv.w;
      }
    }
    __syncthreads();
  }

  // block-reduce rowsums (reuse au)
  #pragma unroll
  for (int i = 0; i < 7; ++i) au[i * 257 + t] = rs[i];
  __syncthreads();
  for (int off = 128; off >= 1; off >>= 1){
    if (t < off){
      #pragma unroll
      for (int i = 0; i < 7; ++i) au[i * 257 + t] += au[i * 257 + t + off];
    }
    __syncthreads();
  }
  if (t < 7) atomicAdd(&rowsumbuf[b * S_ + t], au[t * 257]);
  if (t < 224){
    float* up = updbuf + (size_t)(b * S_ + pi) * 32 + pc4 * 4;
    atomicAdd(up + 0, ux); atomicAdd(up + 1, uy);
    atomicAdd(up + 2, uz); atomicAdd(up + 3, uw);
  }
}

// ---------------------------------------------------------------- fused slot finalize (C) + next-iter prep (A)
__global__ __launch_bounds__(256) void slot_update(
    const float* __restrict__ slots_init,
    float* __restrict__ slotsbuf, float* __restrict__ updbuf, float* __restrict__ rowsumbuf,
    float* __restrict__ qbuf,
    const float* __restrict__ Wq,
    const float* __restrict__ lnsg, const float* __restrict__ lnsb,
    const float* __restrict__ gwi, const float* __restrict__ gwh,
    const float* __restrict__ gbi, const float* __restrict__ gbh,
    const float* __restrict__ lnmg, const float* __restrict__ lnmb,
    const float* __restrict__ w1, const float* __restrict__ b1,
    const float* __restrict__ w2, const float* __restrict__ b2,
    float* __restrict__ out0, float* __restrict__ out2,
    int doC, int doA, int isFinal)
{
  int b = blockIdx.x, t = threadIdx.x;
  int i = t >> 5, c = t & 31;
  __shared__ float sPrev[224], sU[224], sNew[224], sT[224], hM[896];
  float snew = 0.f;

  if (doC){
    if (t < 224){
      sPrev[t] = slotsbuf[b * 224 + t];
      sU[t] = updbuf[b * 224 + t] / rowsumbuf[b * S_ + i];
    }
    __syncthreads();
    if (t < 224){
      float gi[3], gh[3];
      #pragma unroll
      for (int x3 = 0; x3 < 3; ++x3){
        int gg = x3 * 32 + c;
        float ai = gbi[gg], ah = gbh[gg];
        #pragma unroll
        for (int d = 0; d < 32; ++d){
          ai += sU[i * 32 + d]    * gwi[gg * 32 + d];
          ah += sPrev[i * 32 + d] * gwh[gg * 32 + d];
        }
        gi[x3] = ai; gh[x3] = ah;
      }
      float r = 1.f / (1.f + __expf(-(gi[0] + gh[0])));
      float z = 1.f / (1.f + __expf(-(gi[1] + gh[1])));
      float n = tanhf(gi[2] + r * gh[2]);
      snew = (1.f - z) * n + z * sPrev[t];
      sNew[t] = snew;
    }
    __syncthreads();
    if (t < 224){                                       // LN_m
      float mu = 0.f, sq = 0.f;
      #pragma unroll
      for (int d = 0; d < 32; ++d){ float v = sNew[i * 32 + d]; mu += v; sq += v * v; }
      mu *= (1.f / 32.f);
      float var = sq * (1.f / 32.f) - mu * mu;
      float rstd = rsqrtf(var + LNEPS_);
      sT[t] = (snew - mu) * rstd * lnmg[c] + lnmb[c];
    }
    __syncthreads();
    if (t < 224){                                       // MLP layer 1 (4 cols/thread)
      #pragma unroll
      for (int kk = 0; kk < 4; ++kk){
        int hc = c + kk * 32;
        float a = b1[hc];
        #pragma unroll
        for (int d = 0; d < 32; ++d) a += sT[i * 32 + d] * w1[hc * 32 + d];
        hM[i * 128 + hc] = fmaxf(a, 0.f);
      }
    }
    __syncthreads();
    if (t < 224){                                       // MLP layer 2 + residual
      float a = b2[c];
      for (int hh = 0; hh < 128; ++hh) a += hM[i * 128 + hh] * w2[c * 128 + hh];
      snew = snew + a;
      slotsbuf[b * 224 + t] = snew;
      if (isFinal){ out0[b * 224 + t] = snew; out2[b * 224 + t] = snew; }
      sNew[t] = snew;
    }
  } else {
    if (t < 224){
      snew = slots_init[b * 224 + t];
      slotsbuf[b * 224 + t] = snew;
      sNew[t] = snew;
    }
  }

  if (doA){
    __syncthreads();
    if (t < 224){                                       // LN_s
      float mu = 0.f, sq = 0.f;
      #pragma unroll
      for (int d = 0; d < 32; ++d){ float v = sNew[i * 32 + d]; mu += v; sq += v * v; }
      mu *= (1.f / 32.f);
      float var = sq * (1.f / 32.f) - mu * mu;
      float rstd = rsqrtf(var + LNEPS_);
      sT[t] = (snew - mu) * rstd * lnsg[c] + lnsb[c];
    }
    __syncthreads();
    if (t < 224){                                       // q = s_ln @ Wq^T ; zero accumulators
      float a = 0.f;
      #pragma unroll
      for (int d = 0; d < 32; ++d) a += sT[i * 32 + d] * Wq[c * 32 + d];
      qbuf[b * 224 + t] = a;
      updbuf[b * 224 + t] = 0.f;
    }
    if (t < 7) rowsumbuf[b * S_ + t] = 0.f;
  }
}

// ---------------------------------------------------------------- final attn normalization -> f32 out
__global__ __launch_bounds__(256) void attn_final(const float* __restrict__ aub,
                                                  const float* __restrict__ rowsumbuf,
                                                  float* __restrict__ out1){
  int idx = blockIdx.x * 256 + threadIdx.x;   // < 64*7*4096
  int bi = idx >> 12;
  out1[idx] = aub[idx] / rowsumbuf[bi];
}

// ----------------------------------------------------------------
extern "C" void kernel_launch(void* const* d_in, const int* in_sizes, int n_in,
                              void* d_out, int out_size, void* d_ws, size_t ws_size,
                              hipStream_t stream)
{
  (void)in_sizes; (void)n_in; (void)out_size; (void)ws_size;
  const float* inp   = (const float*)d_in[0];
  const float* sini  = (const float*)d_in[1];
  const float* lng   = (const float*)d_in[2];
  const float* lnb   = (const float*)d_in[3];
  const float* Wk    = (const float*)d_in[4];
  const float* Wv    = (const float*)d_in[5];
  const float* Wq    = (const float*)d_in[6];
  const float* lnsg  = (const float*)d_in[7];
  const float* lnsb  = (const float*)d_in[8];
  const float* gwi   = (const float*)d_in[9];
  const float* gwh   = (const float*)d_in[10];
  const float* gbi   = (const float*)d_in[11];
  const float* gbh   = (const float*)d_in[12];
  const float* lnmg  = (const float*)d_in[13];
  const float* lnmb  = (const float*)d_in[14];
  const float* w1    = (const float*)d_in[15];
  const float* b1    = (const float*)d_in[16];
  const float* w2    = (const float*)d_in[17];
  const float* b2    = (const float*)d_in[18];

  char* w = (char*)d_ws;
  float* kbuf      = (float*)w; w += (size_t)B_ * N_ * 32 * 4;
  float* vbuf      = (float*)w; w += (size_t)B_ * N_ * 32 * 4;
  float* qbuf      = (float*)w; w += B_ * 224 * 4;
  float* slotsbuf  = (float*)w; w += B_ * 224 * 4;
  float* updbuf    = (float*)w; w += B_ * 224 * 4;
  float* rowsumbuf = (float*)w; w += B_ * S_ * 4;
  float* aubuf     = (float*)w; w += (size_t)B_ * S_ * N_ * 4;

  float* out0 = (float*)d_out;
  float* out1 = out0 + B_ * S_ * D_;
  float* out2 = out1 + B_ * S_ * N_;

  hipLaunchKernelGGL(ln_kv, dim3(1024), dim3(256), 0, stream, inp, Wk, Wv, lng, lnb, kbuf, vbuf);

  // A0: slots <- slots_init, q0, zero accumulators
  hipLaunchKernelGGL(slot_update, dim3(64), dim3(256), 0, stream,
                     sini, slotsbuf, updbuf, rowsumbuf, qbuf, Wq, lnsg, lnsb,
                     gwi, gwh, gbi, gbh, lnmg, lnmb, w1, b1, w2, b2,
                     out0, out2, 0, 1, 0);

  for (int m = 0; m < 4; ++m){
    hipLaunchKernelGGL(attn_acc, dim3(8, 64), dim3(256), 0, stream,
                       kbuf, vbuf, qbuf, updbuf, rowsumbuf, aubuf, (m == 3) ? 1 : 0);
    hipLaunchKernelGGL(slot_update, dim3(64), dim3(256), 0, stream,
                       sini, slotsbuf, updbuf, rowsumbuf, qbuf, Wq, lnsg, lnsb,
                       gwi, gwh, gbi, gbh, lnmg, lnmb, w1, b1, w2, b2,
                       out0, out2, 1, (m < 3) ? 1 : 0, (m == 3) ? 1 : 0);
  }

  hipLaunchKernelGGL(attn_final, dim3((B_ * S_ * N_) / 256), dim3(256), 0, stream,
                     aubuf, rowsumbuf, out1);
}

// Round 3
// 250.950 us; speedup vs baseline: 1.9685x; 1.9685x over previous
//
#include <hip/hip_runtime.h>
#include <stdint.h>

#define B_   64
#define N_   4096
#define H_   128
#define S_   7
#define D_   32
#define SCALE_ 0.17677669529663687f   // 32^-0.5
#define EPS_   1e-8f
#define LNEPS_ 1e-5f

typedef __bf16 bf16x8 __attribute__((ext_vector_type(8)));
typedef float  floatx4 __attribute__((ext_vector_type(4)));

__device__ __forceinline__ uint16_t f2bf(float f){
  union{float f; uint32_t i;} x; x.f = f;
  uint32_t r = x.i + 0x7fffu + ((x.i >> 16) & 1u);   // round-to-nearest-even
  return (uint16_t)(r >> 16);
}

// ---------------------------------------------------------------- LN(inputs) -> k,v projections (MFMA)
// 64 rows per block, 256 threads (4 waves). Grid 4096.
__global__ __launch_bounds__(256) void ln_kv(const float* __restrict__ x,
                                             const float* __restrict__ Wk, const float* __restrict__ Wv,
                                             const float* __restrict__ g,  const float* __restrict__ bta,
                                             float* __restrict__ kb, float* __restrict__ vb){
  __shared__ uint16_t atile[64 * 136];           // bf16 x_ln tile, row stride 136 (272B)
  int t = threadIdx.x;
  int l = t & 63, w = t >> 6;
  size_t rowbase = (size_t)blockIdx.x * 64;

  // ---- B-frags: W (f32) -> bf16 fragments, once per block
  // nt 0,1 -> Wk cols 0..31 ; nt 2,3 -> Wv cols 0..31
  bf16x8 bfr[4][4];                              // [nt][kc]
  #pragma unroll
  for (int nt = 0; nt < 4; ++nt){
    const float* wbase = (nt < 2 ? Wk : Wv) + ((nt & 1) * 16 + (l & 15)) * 128;
    #pragma unroll
    for (int kc = 0; kc < 4; ++kc){
      const float* wr = wbase + kc * 32 + (l >> 4) * 8;
      union { uint16_t u[8]; bf16x8 v; } tmp;
      #pragma unroll
      for (int j = 0; j < 8; ++j) tmp.u[j] = f2bf(wr[j]);
      bfr[nt][kc] = tmp.v;
    }
  }

  // ---- gamma/beta for this thread's 4 columns (cols (t&31)*4 .. +3)
  float4 g4 = reinterpret_cast<const float4*>(g)[t & 31];
  float4 be4 = reinterpret_cast<const float4*>(bta)[t & 31];

  // ---- load + LN + bf16 -> LDS, 8 steps; per step each half-wave owns one row
  const float4* xp = reinterpret_cast<const float4*>(x + rowbase * H_);
  #pragma unroll
  for (int k = 0; k < 8; ++k){
    float4 v = xp[k * 256 + t];                  // coalesced 1KB per wave
    float s  = v.x + v.y + v.z + v.w;
    float s2 = v.x*v.x + v.y*v.y + v.z*v.z + v.w*v.w;
    #pragma unroll
    for (int m = 1; m <= 16; m <<= 1){           // stays within 32-lane half
      s  += __shfl_xor(s,  m);
      s2 += __shfl_xor(s2, m);
    }
    float mean = s * (1.f / 128.f);
    float var  = s2 * (1.f / 128.f) - mean * mean;
    float rstd = rsqrtf(var + LNEPS_);
    float n0 = (v.x - mean) * rstd * g4.x + be4.x;
    float n1 = (v.y - mean) * rstd * g4.y + be4.y;
    float n2 = (v.z - mean) * rstd * g4.z + be4.z;
    float n3 = (v.w - mean) * rstd * g4.w + be4.w;
    int row = 8 * k + (t >> 5);                  // = 8k + 2w + (l>>5)
    uint32_t lo = (uint32_t)f2bf(n0) | ((uint32_t)f2bf(n1) << 16);
    uint32_t hi = (uint32_t)f2bf(n2) | ((uint32_t)f2bf(n3) << 16);
    *reinterpret_cast<uint2*>(&atile[row * 136 + (t & 31) * 4]) = make_uint2(lo, hi);
  }
  __syncthreads();

  // ---- MFMA: wave w -> rows w*16..w*16+15, all 64 out cols
  floatx4 acc[4] = {{0,0,0,0},{0,0,0,0},{0,0,0,0},{0,0,0,0}};
  #pragma unroll
  for (int kc = 0; kc < 4; ++kc){
    bf16x8 afr = *reinterpret_cast<const bf16x8*>(
        &atile[(w * 16 + (l & 15)) * 136 + kc * 32 + (l >> 4) * 8]);
    #pragma unroll
    for (int nt = 0; nt < 4; ++nt)
      acc[nt] = __builtin_amdgcn_mfma_f32_16x16x32_bf16(afr, bfr[nt][kc], acc[nt], 0, 0, 0);
  }

  // ---- store: D lane map col=l&15, row=(l>>4)*4+j
  #pragma unroll
  for (int nt = 0; nt < 4; ++nt){
    float* dst = (nt < 2 ? kb : vb);
    int gc = (nt & 1) * 16 + (l & 15);
    #pragma unroll
    for (int j = 0; j < 4; ++j){
      size_t grow = rowbase + w * 16 + (l >> 4) * 4 + j;
      dst[grow * 32 + gc] = acc[nt][j];
    }
  }
}

// ---------------------------------------------------------------- per-iteration attention accumulation
// grid: (8 chunks, 64 batches), 256 threads. Each block: 512 j's in 2 tiles of 256.
__global__ __launch_bounds__(256) void attn_acc(const float* __restrict__ kb, const float* __restrict__ vb,
                                                const float* __restrict__ qbuf,
                                                float* __restrict__ updbuf, float* __restrict__ rowsumbuf,
                                                float* __restrict__ aub, int lastIter){
  __shared__ float au[S_ * 257];       // [7][257] padded
  __shared__ float vtile[256 * 32];    // [256][32] f32, XOR-swizzled float4 blocks
  int b = blockIdx.y, chunk = blockIdx.x, t = threadIdx.x;

  int rem = t % 56, prt = t / 56;      // valid for t<224
  int pi = rem >> 3, pc4 = rem & 7;

  float rs[7];
  #pragma unroll
  for (int i = 0; i < 7; ++i) rs[i] = 0.f;
  float ux = 0.f, uy = 0.f, uz = 0.f, uw = 0.f;

  const float* qb = qbuf + b * (S_ * D_);           // wave-uniform -> s_load

  for (int tile = 0; tile < 2; ++tile){
    int j = chunk * 512 + tile * 256 + t;
    const float* kr = kb + ((size_t)b * N_ + j) * 32;
    float kf[32];
    #pragma unroll
    for (int p = 0; p < 8; ++p){
      float4 u = *reinterpret_cast<const float4*>(kr + p * 4);
      kf[p*4+0]=u.x; kf[p*4+1]=u.y; kf[p*4+2]=u.z; kf[p*4+3]=u.w;
    }

    float dv[7];
    #pragma unroll
    for (int i = 0; i < 7; ++i){
      const float* qr = qb + i * 32;
      float a = 0.f;
      #pragma unroll
      for (int c = 0; c < 32; ++c) a += qr[c] * kf[c];
      dv[i] = a * SCALE_;
    }
    float mx = dv[0];
    #pragma unroll
    for (int i = 1; i < 7; ++i) mx = fmaxf(mx, dv[i]);
    float p[7]; float sum = 0.f;
    #pragma unroll
    for (int i = 0; i < 7; ++i){ p[i] = __expf(dv[i] - mx); sum += p[i]; }
    float inv = 1.f / sum;
    #pragma unroll
    for (int i = 0; i < 7; ++i){
      p[i] = p[i] * inv + EPS_;
      rs[i] += p[i];
      au[i * 257 + t] = p[i];
    }
    if (lastIter){
      #pragma unroll
      for (int i = 0; i < 7; ++i) aub[(size_t)(b * S_ + i) * N_ + j] = p[i];
    }
    // stage v tile (f32, XOR-swizzled 16B blocks: logical block q4 stored at q4^(t&7))
    const float* vr = vb + ((size_t)b * N_ + j) * 32;
    #pragma unroll
    for (int q4 = 0; q4 < 8; ++q4){
      int blk = q4 ^ (t & 7);
      float4 vv = *reinterpret_cast<const float4*>(vr + q4 * 4);
      *reinterpret_cast<float4*>(&vtile[t * 32 + blk * 4]) = vv;
    }
    __syncthreads();

    if (t < 224){
      const float* aur = au + pi * 257 + prt * 64;
      #pragma unroll 4
      for (int jj0 = 0; jj0 < 64; ++jj0){
        int jj = prt * 64 + jj0;
        float a = aur[jj0];
        int blk = pc4 ^ (jj & 7);
        float4 vv = *reinterpret_cast<const float4*>(&vtile[jj * 32 + blk * 4]);
        ux += a * vv.x; uy += a * vv.y; uz += a * vv.z; uw += a * vv.w;
      }
    }
    __syncthreads();
  }

  // block-reduce rowsums (reuse au)
  #pragma unroll
  for (int i = 0; i < 7; ++i) au[i * 257 + t] = rs[i];
  __syncthreads();
  for (int off = 128; off >= 1; off >>= 1){
    if (t < off){
      #pragma unroll
      for (int i = 0; i < 7; ++i) au[i * 257 + t] += au[i * 257 + t + off];
    }
    __syncthreads();
  }
  if (t < 7) atomicAdd(&rowsumbuf[b * S_ + t], au[t * 257]);
  if (t < 224){
    float* up = updbuf + (size_t)(b * S_ + pi) * 32 + pc4 * 4;
    atomicAdd(up + 0, ux); atomicAdd(up + 1, uy);
    atomicAdd(up + 2, uz); atomicAdd(up + 3, uw);
  }
}

// ---------------------------------------------------------------- fused slot finalize (C) + next-iter prep (A)
__global__ __launch_bounds__(256) void slot_update(
    const float* __restrict__ slots_init,
    float* __restrict__ slotsbuf, float* __restrict__ updbuf, float* __restrict__ rowsumbuf,
    float* __restrict__ qbuf,
    const float* __restrict__ Wq,
    const float* __restrict__ lnsg, const float* __restrict__ lnsb,
    const float* __restrict__ gwi, const float* __restrict__ gwh,
    const float* __restrict__ gbi, const float* __restrict__ gbh,
    const float* __restrict__ lnmg, const float* __restrict__ lnmb,
    const float* __restrict__ w1, const float* __restrict__ b1,
    const float* __restrict__ w2, const float* __restrict__ b2,
    float* __restrict__ out0, float* __restrict__ out2,
    int doC, int doA, int isFinal)
{
  int b = blockIdx.x, t = threadIdx.x;
  int i = t >> 5, c = t & 31;
  __shared__ float sPrev[224], sU[224], sNew[224], sT[224], hM[896];
  float snew = 0.f;

  if (doC){
    if (t < 224){
      sPrev[t] = slotsbuf[b * 224 + t];
      sU[t] = updbuf[b * 224 + t] / rowsumbuf[b * S_ + i];
    }
    __syncthreads();
    if (t < 224){
      float gi[3], gh[3];
      #pragma unroll
      for (int x3 = 0; x3 < 3; ++x3){
        int gg = x3 * 32 + c;
        float ai = gbi[gg], ah = gbh[gg];
        #pragma unroll
        for (int d = 0; d < 32; ++d){
          ai += sU[i * 32 + d]    * gwi[gg * 32 + d];
          ah += sPrev[i * 32 + d] * gwh[gg * 32 + d];
        }
        gi[x3] = ai; gh[x3] = ah;
      }
      float r = 1.f / (1.f + __expf(-(gi[0] + gh[0])));
      float z = 1.f / (1.f + __expf(-(gi[1] + gh[1])));
      float n = tanhf(gi[2] + r * gh[2]);
      snew = (1.f - z) * n + z * sPrev[t];
      sNew[t] = snew;
    }
    __syncthreads();
    if (t < 224){                                       // LN_m
      float mu = 0.f, sq = 0.f;
      #pragma unroll
      for (int d = 0; d < 32; ++d){ float v = sNew[i * 32 + d]; mu += v; sq += v * v; }
      mu *= (1.f / 32.f);
      float var = sq * (1.f / 32.f) - mu * mu;
      float rstd = rsqrtf(var + LNEPS_);
      sT[t] = (snew - mu) * rstd * lnmg[c] + lnmb[c];
    }
    __syncthreads();
    if (t < 224){                                       // MLP layer 1 (4 cols/thread)
      #pragma unroll
      for (int kk = 0; kk < 4; ++kk){
        int hc = c + kk * 32;
        float a = b1[hc];
        #pragma unroll
        for (int d = 0; d < 32; ++d) a += sT[i * 32 + d] * w1[hc * 32 + d];
        hM[i * 128 + hc] = fmaxf(a, 0.f);
      }
    }
    __syncthreads();
    if (t < 224){                                       // MLP layer 2 + residual
      float a = b2[c];
      for (int hh = 0; hh < 128; ++hh) a += hM[i * 128 + hh] * w2[c * 128 + hh];
      snew = snew + a;
      slotsbuf[b * 224 + t] = snew;
      if (isFinal){ out0[b * 224 + t] = snew; out2[b * 224 + t] = snew; }
      sNew[t] = snew;
    }
  } else {
    if (t < 224){
      snew = slots_init[b * 224 + t];
      slotsbuf[b * 224 + t] = snew;
      sNew[t] = snew;
    }
  }

  if (doA){
    __syncthreads();
    if (t < 224){                                       // LN_s
      float mu = 0.f, sq = 0.f;
      #pragma unroll
      for (int d = 0; d < 32; ++d){ float v = sNew[i * 32 + d]; mu += v; sq += v * v; }
      mu *= (1.f / 32.f);
      float var = sq * (1.f / 32.f) - mu * mu;
      float rstd = rsqrtf(var + LNEPS_);
      sT[t] = (snew - mu) * rstd * lnsg[c] + lnsb[c];
    }
    __syncthreads();
    if (t < 224){                                       // q = s_ln @ Wq^T ; zero accumulators
      float a = 0.f;
      #pragma unroll
      for (int d = 0; d < 32; ++d) a += sT[i * 32 + d] * Wq[c * 32 + d];
      qbuf[b * 224 + t] = a;
      updbuf[b * 224 + t] = 0.f;
    }
    if (t < 7) rowsumbuf[b * S_ + t] = 0.f;
  }
}

// ---------------------------------------------------------------- final attn normalization -> f32 out
__global__ __launch_bounds__(256) void attn_final(const float* __restrict__ aub,
                                                  const float* __restrict__ rowsumbuf,
                                                  float* __restrict__ out1){
  int idx = blockIdx.x * 256 + threadIdx.x;   // < 64*7*4096
  int bi = idx >> 12;
  out1[idx] = aub[idx] / rowsumbuf[bi];
}

// ----------------------------------------------------------------
extern "C" void kernel_launch(void* const* d_in, const int* in_sizes, int n_in,
                              void* d_out, int out_size, void* d_ws, size_t ws_size,
                              hipStream_t stream)
{
  (void)in_sizes; (void)n_in; (void)out_size; (void)ws_size;
  const float* inp   = (const float*)d_in[0];
  const float* sini  = (const float*)d_in[1];
  const float* lng   = (const float*)d_in[2];
  const float* lnb   = (const float*)d_in[3];
  const float* Wk    = (const float*)d_in[4];
  const float* Wv    = (const float*)d_in[5];
  const float* Wq    = (const float*)d_in[6];
  const float* lnsg  = (const float*)d_in[7];
  const float* lnsb  = (const float*)d_in[8];
  const float* gwi   = (const float*)d_in[9];
  const float* gwh   = (const float*)d_in[10];
  const float* gbi   = (const float*)d_in[11];
  const float* gbh   = (const float*)d_in[12];
  const float* lnmg  = (const float*)d_in[13];
  const float* lnmb  = (const float*)d_in[14];
  const float* w1    = (const float*)d_in[15];
  const float* b1    = (const float*)d_in[16];
  const float* w2    = (const float*)d_in[17];
  const float* b2    = (const float*)d_in[18];

  char* w = (char*)d_ws;
  float* kbuf      = (float*)w; w += (size_t)B_ * N_ * 32 * 4;
  float* vbuf      = (float*)w; w += (size_t)B_ * N_ * 32 * 4;
  float* qbuf      = (float*)w; w += B_ * 224 * 4;
  float* slotsbuf  = (float*)w; w += B_ * 224 * 4;
  float* updbuf    = (float*)w; w += B_ * 224 * 4;
  float* rowsumbuf = (float*)w; w += B_ * S_ * 4;
  float* aubuf     = (float*)w; w += (size_t)B_ * S_ * N_ * 4;

  float* out0 = (float*)d_out;
  float* out1 = out0 + B_ * S_ * D_;
  float* out2 = out1 + B_ * S_ * N_;

  hipLaunchKernelGGL(ln_kv, dim3(4096), dim3(256), 0, stream, inp, Wk, Wv, lng, lnb, kbuf, vbuf);

  // A0: slots <- slots_init, q0, zero accumulators
  hipLaunchKernelGGL(slot_update, dim3(64), dim3(256), 0, stream,
                     sini, slotsbuf, updbuf, rowsumbuf, qbuf, Wq, lnsg, lnsb,
                     gwi, gwh, gbi, gbh, lnmg, lnmb, w1, b1, w2, b2,
                     out0, out2, 0, 1, 0);

  for (int m = 0; m < 4; ++m){
    hipLaunchKernelGGL(attn_acc, dim3(8, 64), dim3(256), 0, stream,
                       kbuf, vbuf, qbuf, updbuf, rowsumbuf, aubuf, (m == 3) ? 1 : 0);
    hipLaunchKernelGGL(slot_update, dim3(64), dim3(256), 0, stream,
                       sini, slotsbuf, updbuf, rowsumbuf, qbuf, Wq, lnsg, lnsb,
                       gwi, gwh, gbi, gbh, lnmg, lnmb, w1, b1, w2, b2,
                       out0, out2, 1, (m < 3) ? 1 : 0, (m == 3) ? 1 : 0);
  }

  hipLaunchKernelGGL(attn_final, dim3((B_ * S_ * N_) / 256), dim3(256), 0, stream,
                     aubuf, rowsumbuf, out1);
}

// Round 4
// 202.301 us; speedup vs baseline: 2.4419x; 1.2405x over previous
//
#include <hip/hip_runtime.h>
#include <stdint.h>

#define B_   64
#define N_   4096
#define H_   128
#define S_   7
#define D_   32
#define SCALE_ 0.17677669529663687f   // 32^-0.5
#define EPS_   1e-8f
#define LNEPS_ 1e-5f

typedef __bf16 bf16x8 __attribute__((ext_vector_type(8)));
typedef float  floatx4 __attribute__((ext_vector_type(4)));

__device__ __forceinline__ uint32_t cvt2(float a, float b){
  union { __bf16 h[2]; uint32_t u; } r;
  r.h[0] = (__bf16)a; r.h[1] = (__bf16)b;
  return r.u;
}

// ---------------------------------------------------------------- init: precompute W-fragments (g-folded, bf16) + c1/c2
// grid 5 x 256. Blocks 0-3: 1024 threads -> one (nt,kc,l) fragment each (8 bf16).
// Block 4: t<128 -> c1/c2 constants.
__global__ __launch_bounds__(256) void init_w(const float* __restrict__ Wk, const float* __restrict__ Wv,
                                              const float* __restrict__ g,  const float* __restrict__ bta,
                                              uint16_t* __restrict__ fragbuf,
                                              float* __restrict__ c1arr, float* __restrict__ c2arr){
  int tid = blockIdx.x * 256 + threadIdx.x;
  if (blockIdx.x < 4){
    int nt = tid >> 8, kc = (tid >> 6) & 3, l = tid & 63;
    int col = (nt & 1) * 16 + (l & 15);
    int dbase = kc * 32 + (l >> 4) * 8;
    const float* wr = (nt < 2 ? Wk : Wv) + col * 128 + dbase;
    const float* gr = g + dbase;
    uint32_t u[4];
    #pragma unroll
    for (int j = 0; j < 4; ++j)
      u[j] = cvt2(wr[2*j] * gr[2*j], wr[2*j+1] * gr[2*j+1]);
    *reinterpret_cast<uint4*>(fragbuf + (size_t)tid * 8) = make_uint4(u[0], u[1], u[2], u[3]);
  } else {
    int t = threadIdx.x;
    if (t < 128){
      int which = t >> 5, col = t & 31;                 // 0:c1K 1:c2K 2:c1V 3:c2V
      const float* Wb  = (which & 2) ? Wv : Wk;
      const float* vec = (which & 1) ? bta : g;
      float a = 0.f;
      for (int d = 0; d < 128; ++d) a += vec[d] * Wb[col * 128 + d];
      float* dst = (which & 1) ? c2arr : c1arr;
      dst[(which >> 1) * 32 + col] = a;
    }
  }
}

// ---------------------------------------------------------------- LN(inputs) -> k,v via MFMA on raw x (LN folded into epilogue)
// 64 rows per block, 256 threads (4 waves). Grid 4096.
__global__ __launch_bounds__(256) void ln_kv(const float* __restrict__ x,
                                             const uint16_t* __restrict__ fragbuf,
                                             const float* __restrict__ c1arr, const float* __restrict__ c2arr,
                                             float* __restrict__ kb, float* __restrict__ vb){
  __shared__ uint16_t atile[64 * 136];           // bf16 raw-x tile, row stride 136 (272B)
  __shared__ float2 stats[32 * 65];              // [c][row] padded partial (s, s2)
  __shared__ float2 rowstat[64];                 // (rstd, -mu*rstd)
  int t = threadIdx.x;
  int l = t & 63, w = t >> 6;
  size_t rowbase = (size_t)blockIdx.x * 64;

  // ---- B-frags: precomputed, coalesced dwordx4 loads
  bf16x8 bfr[4][4];                              // [nt][kc]
  #pragma unroll
  for (int nt = 0; nt < 4; ++nt)
    #pragma unroll
    for (int kc = 0; kc < 4; ++kc)
      bfr[nt][kc] = *reinterpret_cast<const bf16x8*>(fragbuf + (((nt * 4 + kc) * 64 + l) * 8));

  // ---- per-thread epilogue constants
  float c1c[4], c2c[4];
  #pragma unroll
  for (int nt = 0; nt < 4; ++nt){
    int colk = (nt & 1) * 16 + (l & 15);
    c1c[nt] = c1arr[(nt >> 1) * 32 + colk];
    c2c[nt] = c2arr[(nt >> 1) * 32 + colk];
  }

  // ---- pass1: load raw x, cast bf16 -> LDS, partial stats -> LDS
  const float4* xp = reinterpret_cast<const float4*>(x + rowbase * H_);
  #pragma unroll
  for (int k = 0; k < 8; ++k){
    float4 v = xp[k * 256 + t];                  // coalesced 1KB per wave
    int row = 8 * k + (t >> 5);
    uint32_t lo = cvt2(v.x, v.y);
    uint32_t hi = cvt2(v.z, v.w);
    *reinterpret_cast<uint2*>(&atile[row * 136 + (t & 31) * 4]) = make_uint2(lo, hi);
    float s  = v.x + v.y + v.z + v.w;
    float s2 = v.x*v.x + v.y*v.y + v.z*v.z + v.w*v.w;
    stats[(t & 31) * 65 + row] = make_float2(s, s2);
  }
  __syncthreads();

  // ---- shallow stats reduce: 8 independent LDS reads + 2 shfl levels
  {
    int row = t >> 2, q = t & 3;
    float s = 0.f, s2 = 0.f;
    #pragma unroll
    for (int j = 0; j < 8; ++j){
      float2 p = stats[(q * 8 + j) * 65 + row];
      s += p.x; s2 += p.y;
    }
    s  += __shfl_xor(s, 1);  s2 += __shfl_xor(s2, 1);
    s  += __shfl_xor(s, 2);  s2 += __shfl_xor(s2, 2);
    if (q == 0){
      float mean = s * (1.f / 128.f);
      float var  = s2 * (1.f / 128.f) - mean * mean;
      float rstd = rsqrtf(var + LNEPS_);
      rowstat[row] = make_float2(rstd, -mean * rstd);
    }
  }
  __syncthreads();

  // ---- MFMA: wave w -> rows w*16..w*16+15, all 64 out cols
  floatx4 acc[4] = {{0,0,0,0},{0,0,0,0},{0,0,0,0},{0,0,0,0}};
  #pragma unroll
  for (int kc = 0; kc < 4; ++kc){
    bf16x8 afr = *reinterpret_cast<const bf16x8*>(
        &atile[(w * 16 + (l & 15)) * 136 + kc * 32 + (l >> 4) * 8]);
    #pragma unroll
    for (int nt = 0; nt < 4; ++nt)
      acc[nt] = __builtin_amdgcn_mfma_f32_16x16x32_bf16(afr, bfr[nt][kc], acc[nt], 0, 0, 0);
  }

  // ---- epilogue: k = rstd*acc + (-mu*rstd)*c1 + c2 ; D lane map col=l&15, row=(l>>4)*4+j
  #pragma unroll
  for (int j = 0; j < 4; ++j){
    int rloc = w * 16 + (l >> 4) * 4 + j;
    float2 ab = rowstat[rloc];
    size_t grow = rowbase + rloc;
    #pragma unroll
    for (int nt = 0; nt < 4; ++nt){
      float* dst = (nt < 2 ? kb : vb);
      int gc = (nt & 1) * 16 + (l & 15);
      float val = fmaf(ab.x, acc[nt][j], fmaf(ab.y, c1c[nt], c2c[nt]));
      dst[grow * 32 + gc] = val;
    }
  }
}

// ---------------------------------------------------------------- per-iteration attention accumulation
// grid: (8 chunks, 64 batches), 256 threads. Each block: 512 j's in 2 tiles of 256.
__global__ __launch_bounds__(256) void attn_acc(const float* __restrict__ kb, const float* __restrict__ vb,
                                                const float* __restrict__ qbuf,
                                                float* __restrict__ updbuf, float* __restrict__ rowsumbuf,
                                                float* __restrict__ aub, int lastIter){
  __shared__ float au[S_ * 257];       // [7][257] padded
  __shared__ float vtile[256 * 32];    // [256][32] f32, XOR-swizzled float4 blocks
  int b = blockIdx.y, chunk = blockIdx.x, t = threadIdx.x;

  int rem = t % 56, prt = t / 56;      // valid for t<224
  int pi = rem >> 3, pc4 = rem & 7;

  float rs[7];
  #pragma unroll
  for (int i = 0; i < 7; ++i) rs[i] = 0.f;
  float ux = 0.f, uy = 0.f, uz = 0.f, uw = 0.f;

  const float* qb = qbuf + b * (S_ * D_);           // wave-uniform -> s_load

  for (int tile = 0; tile < 2; ++tile){
    int j = chunk * 512 + tile * 256 + t;
    const float* kr = kb + ((size_t)b * N_ + j) * 32;
    float kf[32];
    #pragma unroll
    for (int p = 0; p < 8; ++p){
      float4 u = *reinterpret_cast<const float4*>(kr + p * 4);
      kf[p*4+0]=u.x; kf[p*4+1]=u.y; kf[p*4+2]=u.z; kf[p*4+3]=u.w;
    }

    float dv[7];
    #pragma unroll
    for (int i = 0; i < 7; ++i){
      const float* qr = qb + i * 32;
      float a = 0.f;
      #pragma unroll
      for (int c = 0; c < 32; ++c) a += qr[c] * kf[c];
      dv[i] = a * SCALE_;
    }
    float mx = dv[0];
    #pragma unroll
    for (int i = 1; i < 7; ++i) mx = fmaxf(mx, dv[i]);
    float p[7]; float sum = 0.f;
    #pragma unroll
    for (int i = 0; i < 7; ++i){ p[i] = __expf(dv[i] - mx); sum += p[i]; }
    float inv = 1.f / sum;
    #pragma unroll
    for (int i = 0; i < 7; ++i){
      p[i] = p[i] * inv + EPS_;
      rs[i] += p[i];
      au[i * 257 + t] = p[i];
    }
    if (lastIter){
      #pragma unroll
      for (int i = 0; i < 7; ++i) aub[(size_t)(b * S_ + i) * N_ + j] = p[i];
    }
    // stage v tile (f32, XOR-swizzled 16B blocks: logical block q4 stored at q4^(t&7))
    const float* vr = vb + ((size_t)b * N_ + j) * 32;
    #pragma unroll
    for (int q4 = 0; q4 < 8; ++q4){
      int blk = q4 ^ (t & 7);
      float4 vv = *reinterpret_cast<const float4*>(vr + q4 * 4);
      *reinterpret_cast<float4*>(&vtile[t * 32 + blk * 4]) = vv;
    }
    __syncthreads();

    if (t < 224){
      const float* aur = au + pi * 257 + prt * 64;
      #pragma unroll 4
      for (int jj0 = 0; jj0 < 64; ++jj0){
        int jj = prt * 64 + jj0;
        float a = aur[jj0];
        int blk = pc4 ^ (jj & 7);
        float4 vv = *reinterpret_cast<const float4*>(&vtile[jj * 32 + blk * 4]);
        ux += a * vv.x; uy += a * vv.y; uz += a * vv.z; uw += a * vv.w;
      }
    }
    __syncthreads();
  }

  // block-reduce rowsums (reuse au)
  #pragma unroll
  for (int i = 0; i < 7; ++i) au[i * 257 + t] = rs[i];
  __syncthreads();
  for (int off = 128; off >= 1; off >>= 1){
    if (t < off){
      #pragma unroll
      for (int i = 0; i < 7; ++i) au[i * 257 + t] += au[i * 257 + t + off];
    }
    __syncthreads();
  }
  if (t < 7) atomicAdd(&rowsumbuf[b * S_ + t], au[t * 257]);
  if (t < 224){
    float* up = updbuf + (size_t)(b * S_ + pi) * 32 + pc4 * 4;
    atomicAdd(up + 0, ux); atomicAdd(up + 1, uy);
    atomicAdd(up + 2, uz); atomicAdd(up + 3, uw);
  }
}

// ---------------------------------------------------------------- fused slot finalize (C) + next-iter prep (A)
__global__ __launch_bounds__(256) void slot_update(
    const float* __restrict__ slots_init,
    float* __restrict__ slotsbuf, float* __restrict__ updbuf, float* __restrict__ rowsumbuf,
    float* __restrict__ qbuf,
    const float* __restrict__ Wq,
    const float* __restrict__ lnsg, const float* __restrict__ lnsb,
    const float* __restrict__ gwi, const float* __restrict__ gwh,
    const float* __restrict__ gbi, const float* __restrict__ gbh,
    const float* __restrict__ lnmg, const float* __restrict__ lnmb,
    const float* __restrict__ w1, const float* __restrict__ b1,
    const float* __restrict__ w2, const float* __restrict__ b2,
    float* __restrict__ out0, float* __restrict__ out2,
    int doC, int doA, int isFinal)
{
  int b = blockIdx.x, t = threadIdx.x;
  int i = t >> 5, c = t & 31;
  __shared__ float sPrev[224], sU[224], sNew[224], sT[224], hM[896];
  float snew = 0.f;

  if (doC){
    if (t < 224){
      sPrev[t] = slotsbuf[b * 224 + t];
      sU[t] = updbuf[b * 224 + t] / rowsumbuf[b * S_ + i];
    }
    __syncthreads();
    if (t < 224){
      float gi[3], gh[3];
      #pragma unroll
      for (int x3 = 0; x3 < 3; ++x3){
        int gg = x3 * 32 + c;
        float ai = gbi[gg], ah = gbh[gg];
        #pragma unroll
        for (int d = 0; d < 32; ++d){
          ai += sU[i * 32 + d]    * gwi[gg * 32 + d];
          ah += sPrev[i * 32 + d] * gwh[gg * 32 + d];
        }
        gi[x3] = ai; gh[x3] = ah;
      }
      float r = 1.f / (1.f + __expf(-(gi[0] + gh[0])));
      float z = 1.f / (1.f + __expf(-(gi[1] + gh[1])));
      float n = tanhf(gi[2] + r * gh[2]);
      snew = (1.f - z) * n + z * sPrev[t];
      sNew[t] = snew;
    }
    __syncthreads();
    if (t < 224){                                       // LN_m
      float mu = 0.f, sq = 0.f;
      #pragma unroll
      for (int d = 0; d < 32; ++d){ float v = sNew[i * 32 + d]; mu += v; sq += v * v; }
      mu *= (1.f / 32.f);
      float var = sq * (1.f / 32.f) - mu * mu;
      float rstd = rsqrtf(var + LNEPS_);
      sT[t] = (snew - mu) * rstd * lnmg[c] + lnmb[c];
    }
    __syncthreads();
    if (t < 224){                                       // MLP layer 1 (4 cols/thread)
      #pragma unroll
      for (int kk = 0; kk < 4; ++kk){
        int hc = c + kk * 32;
        float a = b1[hc];
        #pragma unroll
        for (int d = 0; d < 32; ++d) a += sT[i * 32 + d] * w1[hc * 32 + d];
        hM[i * 128 + hc] = fmaxf(a, 0.f);
      }
    }
    __syncthreads();
    if (t < 224){                                       // MLP layer 2 + residual
      float a = b2[c];
      for (int hh = 0; hh < 128; ++hh) a += hM[i * 128 + hh] * w2[c * 128 + hh];
      snew = snew + a;
      slotsbuf[b * 224 + t] = snew;
      if (isFinal){ out0[b * 224 + t] = snew; out2[b * 224 + t] = snew; }
      sNew[t] = snew;
    }
  } else {
    if (t < 224){
      snew = slots_init[b * 224 + t];
      slotsbuf[b * 224 + t] = snew;
      sNew[t] = snew;
    }
  }

  if (doA){
    __syncthreads();
    if (t < 224){                                       // LN_s
      float mu = 0.f, sq = 0.f;
      #pragma unroll
      for (int d = 0; d < 32; ++d){ float v = sNew[i * 32 + d]; mu += v; sq += v * v; }
      mu *= (1.f / 32.f);
      float var = sq * (1.f / 32.f) - mu * mu;
      float rstd = rsqrtf(var + LNEPS_);
      sT[t] = (snew - mu) * rstd * lnsg[c] + lnsb[c];
    }
    __syncthreads();
    if (t < 224){                                       // q = s_ln @ Wq^T ; zero accumulators
      float a = 0.f;
      #pragma unroll
      for (int d = 0; d < 32; ++d) a += sT[i * 32 + d] * Wq[c * 32 + d];
      qbuf[b * 224 + t] = a;
      updbuf[b * 224 + t] = 0.f;
    }
    if (t < 7) rowsumbuf[b * S_ + t] = 0.f;
  }
}

// ---------------------------------------------------------------- final attn normalization -> f32 out
__global__ __launch_bounds__(256) void attn_final(const float* __restrict__ aub,
                                                  const float* __restrict__ rowsumbuf,
                                                  float* __restrict__ out1){
  int idx = blockIdx.x * 256 + threadIdx.x;   // < 64*7*4096
  int bi = idx >> 12;
  out1[idx] = aub[idx] / rowsumbuf[bi];
}

// ----------------------------------------------------------------
extern "C" void kernel_launch(void* const* d_in, const int* in_sizes, int n_in,
                              void* d_out, int out_size, void* d_ws, size_t ws_size,
                              hipStream_t stream)
{
  (void)in_sizes; (void)n_in; (void)out_size; (void)ws_size;
  const float* inp   = (const float*)d_in[0];
  const float* sini  = (const float*)d_in[1];
  const float* lng   = (const float*)d_in[2];
  const float* lnb   = (const float*)d_in[3];
  const float* Wk    = (const float*)d_in[4];
  const float* Wv    = (const float*)d_in[5];
  const float* Wq    = (const float*)d_in[6];
  const float* lnsg  = (const float*)d_in[7];
  const float* lnsb  = (const float*)d_in[8];
  const float* gwi   = (const float*)d_in[9];
  const float* gwh   = (const float*)d_in[10];
  const float* gbi   = (const float*)d_in[11];
  const float* gbh   = (const float*)d_in[12];
  const float* lnmg  = (const float*)d_in[13];
  const float* lnmb  = (const float*)d_in[14];
  const float* w1    = (const float*)d_in[15];
  const float* b1    = (const float*)d_in[16];
  const float* w2    = (const float*)d_in[17];
  const float* b2    = (const float*)d_in[18];

  char* w = (char*)d_ws;
  float* kbuf      = (float*)w; w += (size_t)B_ * N_ * 32 * 4;
  float* vbuf      = (float*)w; w += (size_t)B_ * N_ * 32 * 4;
  float* qbuf      = (float*)w; w += B_ * 224 * 4;
  float* slotsbuf  = (float*)w; w += B_ * 224 * 4;
  float* updbuf    = (float*)w; w += B_ * 224 * 4;
  float* rowsumbuf = (float*)w; w += B_ * S_ * 4;
  float* aubuf     = (float*)w; w += (size_t)B_ * S_ * N_ * 4;
  uint16_t* fragbuf= (uint16_t*)w; w += 8192 * 2;
  float* c1arr     = (float*)w; w += 64 * 4;
  float* c2arr     = (float*)w; w += 64 * 4;

  float* out0 = (float*)d_out;
  float* out1 = out0 + B_ * S_ * D_;
  float* out2 = out1 + B_ * S_ * N_;

  hipLaunchKernelGGL(init_w, dim3(5), dim3(256), 0, stream, Wk, Wv, lng, lnb, fragbuf, c1arr, c2arr);
  hipLaunchKernelGGL(ln_kv, dim3(4096), dim3(256), 0, stream, inp, fragbuf, c1arr, c2arr, kbuf, vbuf);

  // A0: slots <- slots_init, q0, zero accumulators
  hipLaunchKernelGGL(slot_update, dim3(64), dim3(256), 0, stream,
                     sini, slotsbuf, updbuf, rowsumbuf, qbuf, Wq, lnsg, lnsb,
                     gwi, gwh, gbi, gbh, lnmg, lnmb, w1, b1, w2, b2,
                     out0, out2, 0, 1, 0);

  for (int m = 0; m < 4; ++m){
    hipLaunchKernelGGL(attn_acc, dim3(8, 64), dim3(256), 0, stream,
                       kbuf, vbuf, qbuf, updbuf, rowsumbuf, aubuf, (m == 3) ? 1 : 0);
    hipLaunchKernelGGL(slot_update, dim3(64), dim3(256), 0, stream,
                       sini, slotsbuf, updbuf, rowsumbuf, qbuf, Wq, lnsg, lnsb,
                       gwi, gwh, gbi, gbh, lnmg, lnmb, w1, b1, w2, b2,
                       out0, out2, 1, (m < 3) ? 1 : 0, (m == 3) ? 1 : 0);
  }

  hipLaunchKernelGGL(attn_final, dim3((B_ * S_ * N_) / 256), dim3(256), 0, stream,
                     aubuf, rowsumbuf, out1);
}

// Round 5
// 185.680 us; speedup vs baseline: 2.6605x; 1.0895x over previous
//
#include <hip/hip_runtime.h>
#include <stdint.h>

#define B_   64
#define N_   4096
#define H_   128
#define S_   7
#define D_   32
#define SCALE_ 0.17677669529663687f   // 32^-0.5
#define EPS_   1e-8f
#define LNEPS_ 1e-5f

typedef __bf16 bf16x8 __attribute__((ext_vector_type(8)));
typedef float  floatx4 __attribute__((ext_vector_type(4)));

__device__ __forceinline__ uint32_t cvt2(float a, float b){
  union { __bf16 h[2]; uint32_t u; } r;
  r.h[0] = (__bf16)a; r.h[1] = (__bf16)b;
  return r.u;
}
__device__ __forceinline__ float bfLO(uint32_t u){ union{uint32_t i; float f;} x; x.i = u << 16;         return x.f; }
__device__ __forceinline__ float bfHI(uint32_t u){ union{uint32_t i; float f;} x; x.i = u & 0xffff0000u; return x.f; }
__device__ __forceinline__ void up8(uint4 u, float* o){
  o[0]=bfLO(u.x); o[1]=bfHI(u.x); o[2]=bfLO(u.y); o[3]=bfHI(u.y);
  o[4]=bfLO(u.z); o[5]=bfHI(u.z); o[6]=bfLO(u.w); o[7]=bfHI(u.w);
}

// ---------------------------------------------------------------- init: precompute W-fragments (g-folded, bf16) + c1/c2
__global__ __launch_bounds__(256) void init_w(const float* __restrict__ Wk, const float* __restrict__ Wv,
                                              const float* __restrict__ g,  const float* __restrict__ bta,
                                              uint16_t* __restrict__ fragbuf,
                                              float* __restrict__ c1arr, float* __restrict__ c2arr){
  int tid = blockIdx.x * 256 + threadIdx.x;
  if (blockIdx.x < 4){
    int nt = tid >> 8, kc = (tid >> 6) & 3, l = tid & 63;
    int col = (nt & 1) * 16 + (l & 15);
    int dbase = kc * 32 + (l >> 4) * 8;
    const float* wr = (nt < 2 ? Wk : Wv) + col * 128 + dbase;
    const float* gr = g + dbase;
    uint32_t u[4];
    #pragma unroll
    for (int j = 0; j < 4; ++j)
      u[j] = cvt2(wr[2*j] * gr[2*j], wr[2*j+1] * gr[2*j+1]);
    *reinterpret_cast<uint4*>(fragbuf + (size_t)tid * 8) = make_uint4(u[0], u[1], u[2], u[3]);
  } else {
    int t = threadIdx.x;
    if (t < 128){
      int which = t >> 5, col = t & 31;                 // 0:c1K 1:c2K 2:c1V 3:c2V
      const float* Wb  = (which & 2) ? Wv : Wk;
      const float* vec = (which & 1) ? bta : g;
      float a = 0.f;
      for (int d = 0; d < 128; ++d) a += vec[d] * Wb[col * 128 + d];
      float* dst = (which & 1) ? c2arr : c1arr;
      dst[(which >> 1) * 32 + col] = a;
    }
  }
}

// ---------------------------------------------------------------- LN(inputs) -> k,v via MFMA on raw x (LN folded into epilogue)
// 64 rows per block, 256 threads (4 waves). Grid 4096. k/v stored bf16.
__global__ __launch_bounds__(256) void ln_kv(const float* __restrict__ x,
                                             const uint16_t* __restrict__ fragbuf,
                                             const float* __restrict__ c1arr, const float* __restrict__ c2arr,
                                             uint16_t* __restrict__ kb, uint16_t* __restrict__ vb){
  __shared__ union {
    uint16_t atile[64 * 136];          // bf16 raw-x tile, row stride 136 (272B)
    float    rep[4352];                // repack area: k[64][34], v at +2176
  } sh;
  __shared__ float2 stats[32 * 65];    // [c][row] padded partial (s, s2)
  __shared__ float2 rowstat[64];       // (rstd, -mu*rstd)
  int t = threadIdx.x;
  int l = t & 63, w = t >> 6;
  size_t rowbase = (size_t)blockIdx.x * 64;

  // ---- B-frags: precomputed, coalesced dwordx4 loads
  bf16x8 bfr[4][4];                    // [nt][kc]
  #pragma unroll
  for (int nt = 0; nt < 4; ++nt)
    #pragma unroll
    for (int kc = 0; kc < 4; ++kc)
      bfr[nt][kc] = *reinterpret_cast<const bf16x8*>(fragbuf + (((nt * 4 + kc) * 64 + l) * 8));

  // ---- per-thread epilogue constants
  float c1c[4], c2c[4];
  #pragma unroll
  for (int nt = 0; nt < 4; ++nt){
    int colk = (nt & 1) * 16 + (l & 15);
    c1c[nt] = c1arr[(nt >> 1) * 32 + colk];
    c2c[nt] = c2arr[(nt >> 1) * 32 + colk];
  }

  // ---- pass1: load raw x, cast bf16 -> LDS, partial stats -> LDS
  const float4* xp = reinterpret_cast<const float4*>(x + rowbase * H_);
  #pragma unroll
  for (int k = 0; k < 8; ++k){
    float4 v = xp[k * 256 + t];        // coalesced 1KB per wave
    int row = 8 * k + (t >> 5);
    uint32_t lo = cvt2(v.x, v.y);
    uint32_t hi = cvt2(v.z, v.w);
    *reinterpret_cast<uint2*>(&sh.atile[row * 136 + (t & 31) * 4]) = make_uint2(lo, hi);
    float s  = v.x + v.y + v.z + v.w;
    float s2 = v.x*v.x + v.y*v.y + v.z*v.z + v.w*v.w;
    stats[(t & 31) * 65 + row] = make_float2(s, s2);
  }
  __syncthreads();

  // ---- shallow stats reduce: 8 independent LDS reads + 2 shfl levels
  {
    int row = t >> 2, q = t & 3;
    float s = 0.f, s2 = 0.f;
    #pragma unroll
    for (int j = 0; j < 8; ++j){
      float2 p = stats[(q * 8 + j) * 65 + row];
      s += p.x; s2 += p.y;
    }
    s  += __shfl_xor(s, 1);  s2 += __shfl_xor(s2, 1);
    s  += __shfl_xor(s, 2);  s2 += __shfl_xor(s2, 2);
    if (q == 0){
      float mean = s * (1.f / 128.f);
      float var  = s2 * (1.f / 128.f) - mean * mean;
      float rstd = rsqrtf(var + LNEPS_);
      rowstat[row] = make_float2(rstd, -mean * rstd);
    }
  }
  __syncthreads();

  // ---- MFMA: wave w -> rows w*16..w*16+15, all 64 out cols
  floatx4 acc[4] = {{0,0,0,0},{0,0,0,0},{0,0,0,0},{0,0,0,0}};
  #pragma unroll
  for (int kc = 0; kc < 4; ++kc){
    bf16x8 afr = *reinterpret_cast<const bf16x8*>(
        &sh.atile[(w * 16 + (l & 15)) * 136 + kc * 32 + (l >> 4) * 8]);
    #pragma unroll
    for (int nt = 0; nt < 4; ++nt)
      acc[nt] = __builtin_amdgcn_mfma_f32_16x16x32_bf16(afr, bfr[nt][kc], acc[nt], 0, 0, 0);
  }
  __syncthreads();                     // atile dead; rep aliases it

  // ---- epilogue: k = rstd*acc + (-mu*rstd)*c1 + c2 -> LDS repack area
  #pragma unroll
  for (int j = 0; j < 4; ++j){
    int rloc = w * 16 + (l >> 4) * 4 + j;
    float2 ab = rowstat[rloc];
    #pragma unroll
    for (int nt = 0; nt < 4; ++nt){
      int base = (nt < 2) ? 0 : 2176;
      int gc = (nt & 1) * 16 + (l & 15);
      sh.rep[base + rloc * 34 + gc] = fmaf(ab.x, acc[nt][j], fmaf(ab.y, c1c[nt], c2c[nt]));
    }
  }
  __syncthreads();

  // ---- pack bf16 pairs, coalesced uint32 stores
  uint32_t* kout = reinterpret_cast<uint32_t*>(kb + rowbase * 32);
  uint32_t* vout = reinterpret_cast<uint32_t*>(vb + rowbase * 32);
  #pragma unroll
  for (int it = 0; it < 4; ++it){
    int lin = it * 256 + t;
    int row = lin >> 4, wd = (lin & 15) * 2;
    kout[lin] = cvt2(sh.rep[row * 34 + wd],        sh.rep[row * 34 + wd + 1]);
    vout[lin] = cvt2(sh.rep[2176 + row * 34 + wd], sh.rep[2176 + row * 34 + wd + 1]);
  }
}

// ---------------------------------------------------------------- per-iteration attention accumulation (bf16 k/v)
// grid: (8 chunks, 64 batches), 256 threads. Each block: 512 j's in 2 tiles of 256.
__global__ __launch_bounds__(256) void attn_acc(const uint16_t* __restrict__ kb, const uint16_t* __restrict__ vb,
                                                const float* __restrict__ qbuf,
                                                float* __restrict__ updbuf, float* __restrict__ rowsumbuf,
                                                float* __restrict__ aub, int lastIter){
  __shared__ float au[S_ * 257];       // [7][257] padded
  __shared__ float vtile[256 * 32];    // [256][32] f32, XOR-swizzled float4 blocks
  int b = blockIdx.y, chunk = blockIdx.x, t = threadIdx.x;

  int rem = t % 56, prt = t / 56;      // valid for t<224
  int pi = rem >> 3, pc4 = rem & 7;

  float rs[7];
  #pragma unroll
  for (int i = 0; i < 7; ++i) rs[i] = 0.f;
  float ux = 0.f, uy = 0.f, uz = 0.f, uw = 0.f;

  const float* qb = qbuf + b * (S_ * D_);           // wave-uniform -> s_load

  for (int tile = 0; tile < 2; ++tile){
    int j = chunk * 512 + tile * 256 + t;
    const uint4* kr = reinterpret_cast<const uint4*>(kb + ((size_t)b * N_ + j) * 32);
    float kf[32];
    #pragma unroll
    for (int p = 0; p < 4; ++p) up8(kr[p], kf + p * 8);

    float dv[7];
    #pragma unroll
    for (int i = 0; i < 7; ++i){
      const float* qr = qb + i * 32;
      float a = 0.f;
      #pragma unroll
      for (int c = 0; c < 32; ++c) a += qr[c] * kf[c];
      dv[i] = a * SCALE_;
    }
    float mx = dv[0];
    #pragma unroll
    for (int i = 1; i < 7; ++i) mx = fmaxf(mx, dv[i]);
    float p[7]; float sum = 0.f;
    #pragma unroll
    for (int i = 0; i < 7; ++i){ p[i] = __expf(dv[i] - mx); sum += p[i]; }
    float inv = 1.f / sum;
    #pragma unroll
    for (int i = 0; i < 7; ++i){
      p[i] = p[i] * inv + EPS_;
      rs[i] += p[i];
      au[i * 257 + t] = p[i];
    }
    if (lastIter){
      #pragma unroll
      for (int i = 0; i < 7; ++i) aub[(size_t)(b * S_ + i) * N_ + j] = p[i];
    }
    // stage v tile (f32, XOR-swizzled 16B blocks: logical block q4 stored at q4^(t&7))
    const uint4* vr = reinterpret_cast<const uint4*>(vb + ((size_t)b * N_ + j) * 32);
    float vf[32];
    #pragma unroll
    for (int p = 0; p < 4; ++p) up8(vr[p], vf + p * 8);
    #pragma unroll
    for (int q4 = 0; q4 < 8; ++q4){
      int blk = q4 ^ (t & 7);
      float4 vv = make_float4(vf[q4*4], vf[q4*4+1], vf[q4*4+2], vf[q4*4+3]);
      *reinterpret_cast<float4*>(&vtile[t * 32 + blk * 4]) = vv;
    }
    __syncthreads();

    if (t < 224){
      const float* aur = au + pi * 257 + prt * 64;
      #pragma unroll 4
      for (int jj0 = 0; jj0 < 64; ++jj0){
        int jj = prt * 64 + jj0;
        float a = aur[jj0];
        int blk = pc4 ^ (jj & 7);
        float4 vv = *reinterpret_cast<const float4*>(&vtile[jj * 32 + blk * 4]);
        ux += a * vv.x; uy += a * vv.y; uz += a * vv.z; uw += a * vv.w;
      }
    }
    __syncthreads();
  }

  // block-reduce rowsums (reuse au)
  #pragma unroll
  for (int i = 0; i < 7; ++i) au[i * 257 + t] = rs[i];
  __syncthreads();
  for (int off = 128; off >= 1; off >>= 1){
    if (t < off){
      #pragma unroll
      for (int i = 0; i < 7; ++i) au[i * 257 + t] += au[i * 257 + t + off];
    }
    __syncthreads();
  }
  if (t < 7) atomicAdd(&rowsumbuf[b * S_ + t], au[t * 257]);
  if (t < 224){
    float* up = updbuf + (size_t)(b * S_ + pi) * 32 + pc4 * 4;
    atomicAdd(up + 0, ux); atomicAdd(up + 1, uy);
    atomicAdd(up + 2, uz); atomicAdd(up + 3, uw);
  }
}

// ---------------------------------------------------------------- fused slot finalize (C) + next-iter prep (A)
__global__ __launch_bounds__(256) void slot_update(
    const float* __restrict__ slots_init,
    float* __restrict__ slotsbuf, float* __restrict__ updbuf, float* __restrict__ rowsumbuf,
    float* __restrict__ qbuf,
    const float* __restrict__ Wq,
    const float* __restrict__ lnsg, const float* __restrict__ lnsb,
    const float* __restrict__ gwi, const float* __restrict__ gwh,
    const float* __restrict__ gbi, const float* __restrict__ gbh,
    const float* __restrict__ lnmg, const float* __restrict__ lnmb,
    const float* __restrict__ w1, const float* __restrict__ b1,
    const float* __restrict__ w2, const float* __restrict__ b2,
    float* __restrict__ out0, float* __restrict__ out2,
    int doC, int doA, int isFinal)
{
  int b = blockIdx.x, t = threadIdx.x;
  int i = t >> 5, c = t & 31;
  __shared__ float sPrev[224], sU[224], sNew[224], sT[224], hM[896];
  float snew = 0.f;

  if (doC){
    if (t < 224){
      sPrev[t] = slotsbuf[b * 224 + t];
      sU[t] = updbuf[b * 224 + t] / rowsumbuf[b * S_ + i];
    }
    __syncthreads();
    if (t < 224){
      float gi[3], gh[3];
      #pragma unroll
      for (int x3 = 0; x3 < 3; ++x3){
        int gg = x3 * 32 + c;
        float ai = gbi[gg], ah = gbh[gg];
        #pragma unroll
        for (int d = 0; d < 32; ++d){
          ai += sU[i * 32 + d]    * gwi[gg * 32 + d];
          ah += sPrev[i * 32 + d] * gwh[gg * 32 + d];
        }
        gi[x3] = ai; gh[x3] = ah;
      }
      float r = 1.f / (1.f + __expf(-(gi[0] + gh[0])));
      float z = 1.f / (1.f + __expf(-(gi[1] + gh[1])));
      float n = tanhf(gi[2] + r * gh[2]);
      snew = (1.f - z) * n + z * sPrev[t];
      sNew[t] = snew;
    }
    __syncthreads();
    if (t < 224){                                       // LN_m
      float mu = 0.f, sq = 0.f;
      #pragma unroll
      for (int d = 0; d < 32; ++d){ float v = sNew[i * 32 + d]; mu += v; sq += v * v; }
      mu *= (1.f / 32.f);
      float var = sq * (1.f / 32.f) - mu * mu;
      float rstd = rsqrtf(var + LNEPS_);
      sT[t] = (snew - mu) * rstd * lnmg[c] + lnmb[c];
    }
    __syncthreads();
    if (t < 224){                                       // MLP layer 1 (4 cols/thread)
      #pragma unroll
      for (int kk = 0; kk < 4; ++kk){
        int hc = c + kk * 32;
        float a = b1[hc];
        #pragma unroll
        for (int d = 0; d < 32; ++d) a += sT[i * 32 + d] * w1[hc * 32 + d];
        hM[i * 128 + hc] = fmaxf(a, 0.f);
      }
    }
    __syncthreads();
    if (t < 224){                                       // MLP layer 2 + residual (4 indep accumulators)
      float a0 = 0.f, a1 = 0.f, a2 = 0.f, a3 = 0.f;
      for (int hh = 0; hh < 128; hh += 4){
        a0 += hM[i * 128 + hh    ] * w2[c * 128 + hh    ];
        a1 += hM[i * 128 + hh + 1] * w2[c * 128 + hh + 1];
        a2 += hM[i * 128 + hh + 2] * w2[c * 128 + hh + 2];
        a3 += hM[i * 128 + hh + 3] * w2[c * 128 + hh + 3];
      }
      snew = snew + b2[c] + ((a0 + a1) + (a2 + a3));
      slotsbuf[b * 224 + t] = snew;
      if (isFinal){ out0[b * 224 + t] = snew; out2[b * 224 + t] = snew; }
      sNew[t] = snew;
    }
  } else {
    if (t < 224){
      snew = slots_init[b * 224 + t];
      slotsbuf[b * 224 + t] = snew;
      sNew[t] = snew;
    }
  }

  if (doA){
    __syncthreads();
    if (t < 224){                                       // LN_s
      float mu = 0.f, sq = 0.f;
      #pragma unroll
      for (int d = 0; d < 32; ++d){ float v = sNew[i * 32 + d]; mu += v; sq += v * v; }
      mu *= (1.f / 32.f);
      float var = sq * (1.f / 32.f) - mu * mu;
      float rstd = rsqrtf(var + LNEPS_);
      sT[t] = (snew - mu) * rstd * lnsg[c] + lnsb[c];
    }
    __syncthreads();
    if (t < 224){                                       // q = s_ln @ Wq^T ; zero accumulators
      float a = 0.f;
      #pragma unroll
      for (int d = 0; d < 32; ++d) a += sT[i * 32 + d] * Wq[c * 32 + d];
      qbuf[b * 224 + t] = a;
      updbuf[b * 224 + t] = 0.f;
    }
    if (t < 7) rowsumbuf[b * S_ + t] = 0.f;
  }
}

// ---------------------------------------------------------------- final attn normalization -> f32 out
__global__ __launch_bounds__(256) void attn_final(const float* __restrict__ aub,
                                                  const float* __restrict__ rowsumbuf,
                                                  float* __restrict__ out1){
  int idx = blockIdx.x * 256 + threadIdx.x;   // < 64*7*4096
  int bi = idx >> 12;
  out1[idx] = aub[idx] / rowsumbuf[bi];
}

// ----------------------------------------------------------------
extern "C" void kernel_launch(void* const* d_in, const int* in_sizes, int n_in,
                              void* d_out, int out_size, void* d_ws, size_t ws_size,
                              hipStream_t stream)
{
  (void)in_sizes; (void)n_in; (void)out_size; (void)ws_size;
  const float* inp   = (const float*)d_in[0];
  const float* sini  = (const float*)d_in[1];
  const float* lng   = (const float*)d_in[2];
  const float* lnb   = (const float*)d_in[3];
  const float* Wk    = (const float*)d_in[4];
  const float* Wv    = (const float*)d_in[5];
  const float* Wq    = (const float*)d_in[6];
  const float* lnsg  = (const float*)d_in[7];
  const float* lnsb  = (const float*)d_in[8];
  const float* gwi   = (const float*)d_in[9];
  const float* gwh   = (const float*)d_in[10];
  const float* gbi   = (const float*)d_in[11];
  const float* gbh   = (const float*)d_in[12];
  const float* lnmg  = (const float*)d_in[13];
  const float* lnmb  = (const float*)d_in[14];
  const float* w1    = (const float*)d_in[15];
  const float* b1    = (const float*)d_in[16];
  const float* w2    = (const float*)d_in[17];
  const float* b2    = (const float*)d_in[18];

  char* w = (char*)d_ws;
  uint16_t* kbuf   = (uint16_t*)w; w += (size_t)B_ * N_ * 32 * 2;
  uint16_t* vbuf   = (uint16_t*)w; w += (size_t)B_ * N_ * 32 * 2;
  float* qbuf      = (float*)w; w += B_ * 224 * 4;
  float* slotsbuf  = (float*)w; w += B_ * 224 * 4;
  float* updbuf    = (float*)w; w += B_ * 224 * 4;
  float* rowsumbuf = (float*)w; w += B_ * S_ * 4;
  float* aubuf     = (float*)w; w += (size_t)B_ * S_ * N_ * 4;
  uint16_t* fragbuf= (uint16_t*)w; w += 8192 * 2;
  float* c1arr     = (float*)w; w += 64 * 4;
  float* c2arr     = (float*)w; w += 64 * 4;

  float* out0 = (float*)d_out;
  float* out1 = out0 + B_ * S_ * D_;
  float* out2 = out1 + B_ * S_ * N_;

  hipLaunchKernelGGL(init_w, dim3(5), dim3(256), 0, stream, Wk, Wv, lng, lnb, fragbuf, c1arr, c2arr);
  hipLaunchKernelGGL(ln_kv, dim3(4096), dim3(256), 0, stream, inp, fragbuf, c1arr, c2arr, kbuf, vbuf);

  // A0: slots <- slots_init, q0, zero accumulators
  hipLaunchKernelGGL(slot_update, dim3(64), dim3(256), 0, stream,
                     sini, slotsbuf, updbuf, rowsumbuf, qbuf, Wq, lnsg, lnsb,
                     gwi, gwh, gbi, gbh, lnmg, lnmb, w1, b1, w2, b2,
                     out0, out2, 0, 1, 0);

  for (int m = 0; m < 4; ++m){
    hipLaunchKernelGGL(attn_acc, dim3(8, 64), dim3(256), 0, stream,
                       kbuf, vbuf, qbuf, updbuf, rowsumbuf, aubuf, (m == 3) ? 1 : 0);
    hipLaunchKernelGGL(slot_update, dim3(64), dim3(256), 0, stream,
                       sini, slotsbuf, updbuf, rowsumbuf, qbuf, Wq, lnsg, lnsb,
                       gwi, gwh, gbi, gbh, lnmg, lnmb, w1, b1, w2, b2,
                       out0, out2, 1, (m < 3) ? 1 : 0, (m == 3) ? 1 : 0);
  }

  hipLaunchKernelGGL(attn_final, dim3((B_ * S_ * N_) / 256), dim3(256), 0, stream,
                     aubuf, rowsumbuf, out1);
}